// Round 7
// baseline (165.767 us; speedup 1.0000x reference)
//
#include <hip/hip_runtime.h>

// Row-wise top-K(32) of relu(A), zero elsewhere. N=8192 fp32 per row.
// One 256-thread block per row.
//   - A is read from global EXACTLY ONCE  (R4: 2nd stream kills L3 residency)
//   - ONE final nt store burst, NOTHING after it  (R5: vm-drain barrier after
//     a store burst costs ~12 us; stores must retire with the kernel)
// touch 1: histogram values > 2.0 (bits>>20, monotonic for positive floats)
//          AND collect all (val,col) > 2.0 into LDS (~186 entries).
// select:  cutoff bin B via wave suffix-scans; exact (val desc, col asc)
//          rank-R boundary (vR,cR); ballot-compact the K selected pairs and
//          build an 8192-bit column mask — all in LDS, all waves redundant.
// emit:    each thread composes its 32 output floats from sel[]/mask (no A
//          re-read) and issues one coalesced nt burst. Kernel ends.
// Exact block-uniform fallback (full histogram + dense emit) for rows where
// speculation fails (< K values > 2.0, or candidate/bin overflow).

constexpr int N     = 8192;
constexpr int K     = 32;
constexpr int NBINS = 2048;      // positive fp32: bits>>20 in [0, 2048)
constexpr int SPEC_BASE = 1024;  // bin(2.0) = 1024; values > 2.0 -> [1024,2048)
constexpr int CAP   = 512;       // candidate list capacity (expected ~186)
constexpr int SLOTS = CAP / 64;
constexpr int BB    = 128;       // compacted cutoff-bin entries (expected ~26)
constexpr int BLOCK = 256;
constexpr int MWORDS = N / 32;   // 256 mask words
constexpr float TSPEC = 2.0f;

typedef float f4 __attribute__((ext_vector_type(4)));

template<int PER>
__device__ __forceinline__ bool find_cutoff(const unsigned* hist, int lane,
                                            int base, int& B, int& G) {
    unsigned s = 0;
    #pragma unroll
    for (int i = 0; i < PER; ++i)
        s += hist[base + lane * PER + ((i + lane) & (PER - 1))];  // staggered
    unsigned acc = s;                       // inclusive suffix sum over lanes
    #pragma unroll
    for (int off = 1; off < 64; off <<= 1) {
        unsigned t = __shfl_down(acc, off, 64);
        if (lane + off < 64) acc += t;
    }
    unsigned long long m = __ballot(acc >= (unsigned)K);
    if (m == 0ull) return false;
    int g = 63 - __clzll((long long)m);     // highest group with suffix >= K
    unsigned above = (g < 63) ? (unsigned)__shfl((int)acc, g + 1, 64) : 0u;
    unsigned h  = (lane < PER) ? hist[base + g * PER + lane] : 0u;
    unsigned a2 = h;                        // within-group suffix
    #pragma unroll
    for (int off = 1; off < 64; off <<= 1) {
        unsigned t = __shfl_down(a2, off, 64);
        if (lane + off < 64) a2 += t;
    }
    unsigned long long m2 = __ballot(above + a2 >= (unsigned)K);
    int bl = 63 - __clzll((long long)m2);
    B = base + g * PER + bl;
    G = (int)(above + (unsigned)__shfl((int)a2, bl, 64)
                    - (unsigned)__shfl((int)h,  bl, 64));
    return true;
}

__global__ __launch_bounds__(BLOCK)
void topk_relu_kernel(const float* __restrict__ A, float* __restrict__ Out) {
    const int row  = blockIdx.x;
    const int tid  = threadIdx.x;
    const int lane = tid & 63;

    __shared__ unsigned hist[NBINS];
    __shared__ float    cv[CAP];
    __shared__ int      cc[CAP];
    __shared__ float    bbv[BB];
    __shared__ int      bbc[BB];
    __shared__ float    sel_v[K];
    __shared__ int      sel_c[K];
    __shared__ unsigned selmask[MWORDS];
    __shared__ unsigned ccnt;

    #pragma unroll
    for (int i = 0; i < (NBINS - SPEC_BASE) / BLOCK; ++i)
        hist[SPEC_BASE + tid + i * BLOCK] = 0u;
    selmask[tid] = 0u;
    if (tid == 0) ccnt = 0u;
    __syncthreads();

    // ---- touch 1: the ONLY global read of A on the fast path ----
    const f4* __restrict__ Arow = reinterpret_cast<const f4*>(A + (size_t)row * N);
    #pragma unroll
    for (int i = 0; i < 8; ++i) {
        f4 v = Arow[i * BLOCK + tid];
        #pragma unroll
        for (int c = 0; c < 4; ++c) {
            float f = v[c];
            if (f > TSPEC) {
                atomicAdd(&hist[__float_as_uint(f) >> 20], 1u);
                unsigned ix = atomicAdd(&ccnt, 1u);
                if (ix < CAP) { cv[ix] = f; cc[ix] = (i * BLOCK + tid) * 4 + c; }
            }
        }
    }
    __syncthreads();

    int B, G;
    bool ok = find_cutoff<16>(hist, lane, SPEC_BASE, B, G);
    const unsigned Call = ccnt;             // block-uniform
    f4* __restrict__ Orow4 = reinterpret_cast<f4*>(Out + (size_t)row * N);

    bool fast = ok && Call <= (unsigned)CAP;
    if (fast) {
        const int R = K - G;
        const int C = (int)Call;
        // ballot-compact bin-B entries (all waves duplicate-identical writes)
        int total = 0;
        #pragma unroll
        for (int s = 0; s < SLOTS; ++s) {
            const int j = lane + s * 64;
            bool flag = false; float fv = 0.0f; int fc = 0;
            if (j < C) {
                fv = cv[j];
                if ((int)(__float_as_uint(fv) >> 20) == B) { flag = true; fc = cc[j]; }
            }
            unsigned long long m = __ballot(flag);
            if (flag) {
                int pos = total + __popcll(m & ((1ull << lane) - 1ull));
                if (pos < BB) { bbv[pos] = fv; bbc[pos] = fc; }
            }
            total += (int)__popcll(m);
        }
        if (total > BB) {
            fast = false;                   // adversarial tie overflow: exact path
        } else {
            const int T = total;            // expected ~26; >= R
            // rank-R boundary (vR, cR) within bin B
            float mv0 = -1.0f, mv1 = -1.0f; int mc0 = 0x7fffffff, mc1 = 0x7fffffff;
            if (lane      < T) { mv0 = bbv[lane];      mc0 = bbc[lane]; }
            if (lane + 64 < T) { mv1 = bbv[lane + 64]; mc1 = bbc[lane + 64]; }
            int r0 = 0, r1 = 0;
            for (int j = 0; j < T; ++j) {   // LDS broadcast reads
                const float vj = bbv[j];
                const int   cj = bbc[j];
                if (vj > mv0 || (vj == mv0 && cj < mc0)) r0++;
                if (vj > mv1 || (vj == mv1 && cj < mc1)) r1++;
            }
            float bv = 0.0f; int bc = -1; bool found = false;
            if (lane      < T && r0 == R - 1) { bv = mv0; bc = mc0; found = true; }
            if (lane + 64 < T && r1 == R - 1) { bv = mv1; bc = mc1; found = true; }
            float vR = __int_as_float(0x7f800000);
            int   cR = -1;
            unsigned long long bm = __ballot(found);
            if (bm != 0ull) {
                int src = (int)__ffsll((long long)bm) - 1;
                vR = __shfl(bv, src, 64);
                cR = __shfl(bc, src, 64);
            }

            // ballot-compact the K selected (val,col) + build the column mask.
            // All waves duplicate-identical; atomicOr is idempotent.
            int nsel = 0;
            #pragma unroll
            for (int s = 0; s < SLOTS; ++s) {
                const int j = lane + s * 64;
                bool flag = false; float fv = 0.0f; int fc = 0;
                if (j < C) {
                    fv = cv[j]; fc = cc[j];
                    flag = (fv > vR) || (fv == vR && fc <= cR);
                }
                unsigned long long m = __ballot(flag);
                if (flag) {
                    int pos = nsel + __popcll(m & ((1ull << lane) - 1ull));
                    if (pos < K) { sel_v[pos] = fv; sel_c[pos] = fc; }
                    atomicOr(&selmask[fc >> 5], 1u << (fc & 31));
                }
                nsel += (int)__popcll(m);
            }
            __syncthreads();   // LDS-only barrier: no global stores outstanding

            // ---- emit: compose from sel[]/mask; ONE nt burst, kernel ends ----
            #pragma unroll
            for (int i = 0; i < 8; ++i) {
                const int q    = i * BLOCK + tid;              // f4 chunk index
                unsigned nib   = (selmask[q >> 3] >> ((q & 7) * 4)) & 0xFu;
                f4 w = {0.0f, 0.0f, 0.0f, 0.0f};
                if (nib) {
                    #pragma unroll 4
                    for (int s = 0; s < K; ++s) {
                        int c = sel_c[s];
                        if ((c >> 2) == q) w[c & 3] = sel_v[s];
                    }
                }
                __builtin_nontemporal_store(w, Orow4 + i * BLOCK + tid);
            }
            return;
        }
    }

    // ---- exact fallback (block-uniform; ~never for N(0,1) rows) ----
    __syncthreads();                        // scan reads done before re-zero
    #pragma unroll
    for (int i = 0; i < NBINS / BLOCK; ++i) hist[tid + i * BLOCK] = 0u;
    if (tid == 0) ccnt = 0u;
    __syncthreads();
    #pragma unroll
    for (int i = 0; i < 8; ++i) {
        f4 v = Arow[i * BLOCK + tid];
        #pragma unroll
        for (int c = 0; c < 4; ++c) {
            float f = v[c];
            if (f > 0.0f) atomicAdd(&hist[__float_as_uint(f) >> 20], 1u);
        }
    }
    __syncthreads();
    if (!find_cutoff<32>(hist, lane, 0, B, G)) { B = -1; G = 0; }
    if (B >= 0) {
        #pragma unroll
        for (int i = 0; i < 8; ++i) {
            f4 v = Arow[i * BLOCK + tid];
            #pragma unroll
            for (int c = 0; c < 4; ++c) {
                float f = v[c];
                if (f > 0.0f && (int)(__float_as_uint(f) >> 20) == B) {
                    unsigned ix = atomicAdd(&ccnt, 1u);
                    if (ix < CAP) { cv[ix] = f; cc[ix] = (i * BLOCK + tid) * 4 + c; }
                }
            }
        }
    }
    __syncthreads();

    float vR = 0.0f;                        // B == -1: keep all positives
    int   cR = -1;
    if (B >= 0) {
        const int R = K - G;
        const int C = (int)min(ccnt, (unsigned)CAP);
        float mv[SLOTS]; int mc[SLOTS]; int rk[SLOTS];
        #pragma unroll
        for (int s = 0; s < SLOTS; ++s) {
            const int j = lane + s * 64;
            if (j < C) { mv[s] = cv[j]; mc[s] = cc[j]; }
            else       { mv[s] = -1.0f; mc[s] = 0x7fffffff; }
            rk[s] = 0;
        }
        for (int j = 0; j < C; ++j) {
            const float vj = cv[j];
            const int   cj = cc[j];
            #pragma unroll
            for (int s = 0; s < SLOTS; ++s)
                if (vj > mv[s] || (vj == mv[s] && cj < mc[s])) rk[s]++;
        }
        float bv = 0.0f; int bc = -1; bool found = false;
        #pragma unroll
        for (int s = 0; s < SLOTS; ++s)
            if (lane + s * 64 < C && rk[s] == R - 1) { bv = mv[s]; bc = mc[s]; found = true; }
        vR = __int_as_float(0x7f800000);
        unsigned long long bm = __ballot(found);
        if (bm != 0ull) {
            int src = (int)__ffsll((long long)bm) - 1;
            vR = __shfl(bv, src, 64);
            cR = __shfl(bc, src, 64);
        }
    }

    // dense emit (fallback only): re-read row (L2-hot) and write everything
    #pragma unroll
    for (int i = 0; i < 8; ++i) {
        f4 v = Arow[i * BLOCK + tid];
        f4 w;
        #pragma unroll
        for (int c = 0; c < 4; ++c) {
            float f   = v[c];
            int   col = (i * BLOCK + tid) * 4 + c;
            w[c] = ((f > vR) || (f == vR && col <= cR)) ? f : 0.0f;
        }
        __builtin_nontemporal_store(w, Orow4 + i * BLOCK + tid);
    }
}

extern "C" void kernel_launch(void* const* d_in, const int* in_sizes, int n_in,
                              void* d_out, int out_size, void* d_ws, size_t ws_size,
                              hipStream_t stream) {
    const float* A   = (const float*)d_in[0];
    float*       Out = (float*)d_out;
    (void)in_sizes; (void)n_in; (void)d_ws; (void)ws_size; (void)out_size;
    topk_relu_kernel<<<dim3(N), dim3(BLOCK), 0, stream>>>(A, Out);
}

// Round 8
// 91.938 us; speedup vs baseline: 1.8030x; 1.8030x over previous
//
#include <hip/hip_runtime.h>

// Row-wise top-K(32) of relu(A), zero elsewhere. N=8192 fp32 per row.
// One 256-thread block per row.
//  - A read from global EXACTLY ONCE   (R4: 2nd stream kills L3 residency)
//  - ONE final nt store burst, NOTHING after it (R5: post-store vm-drain
//    barrier costs ~12 us; stores must retire with the kernel)
//  - O(1)-per-thread emit compose      (R6: per-chunk 32-iter LDS search
//    cost ~3000 cyc/wave -> 165 us; replace with per-owner patch slots)
// Flow: touch1 = hist(values>2.0, bits>>20 bins) + collect (val,col)>2.0
// into LDS (~186). Wave 0 alone: cutoff bin B, exact (val desc, col asc)
// rank-R boundary, then scatters the exactly-K selected pairs into
// per-owner-thread patch slots (owner=(col>>2)&255, <=4 slots, transposed).
// One LDS barrier. Every thread emits its 8 f4 chunks: zero except its own
// patches (static component indexing only). Exact block-uniform fallback
// (full histogram + dense reload-emit) for any speculation failure.

constexpr int N     = 8192;
constexpr int K     = 32;
constexpr int NBINS = 2048;      // positive fp32: bits>>20 in [0, 2048)
constexpr int SPEC_BASE = 1024;  // bin(2.0) = 1024; values > 2.0 -> [1024,2048)
constexpr int CAP   = 512;       // candidate list capacity (expected ~186)
constexpr int SLOTS = CAP / 64;
constexpr int BB    = 128;       // compacted cutoff-bin entries (expected ~26)
constexpr int BLOCK = 256;
constexpr int PSLOT = 4;         // patch slots per owner thread
constexpr float TSPEC = 2.0f;

typedef float f4 __attribute__((ext_vector_type(4)));

template<int PER>
__device__ __forceinline__ bool find_cutoff(const unsigned* hist, int lane,
                                            int base, int& B, int& G) {
    unsigned s = 0;
    #pragma unroll
    for (int i = 0; i < PER; ++i)
        s += hist[base + lane * PER + ((i + lane) & (PER - 1))];  // staggered
    unsigned acc = s;                       // inclusive suffix sum over lanes
    #pragma unroll
    for (int off = 1; off < 64; off <<= 1) {
        unsigned t = __shfl_down(acc, off, 64);
        if (lane + off < 64) acc += t;
    }
    unsigned long long m = __ballot(acc >= (unsigned)K);
    if (m == 0ull) return false;
    int g = 63 - __clzll((long long)m);     // highest group with suffix >= K
    unsigned above = (g < 63) ? (unsigned)__shfl((int)acc, g + 1, 64) : 0u;
    unsigned h  = (lane < PER) ? hist[base + g * PER + lane] : 0u;
    unsigned a2 = h;                        // within-group suffix
    #pragma unroll
    for (int off = 1; off < 64; off <<= 1) {
        unsigned t = __shfl_down(a2, off, 64);
        if (lane + off < 64) a2 += t;
    }
    unsigned long long m2 = __ballot(above + a2 >= (unsigned)K);
    int bl = 63 - __clzll((long long)m2);
    B = base + g * PER + bl;
    G = (int)(above + (unsigned)__shfl((int)a2, bl, 64)
                    - (unsigned)__shfl((int)h,  bl, 64));
    return true;
}

__global__ __launch_bounds__(BLOCK)
void topk_relu_kernel(const float* __restrict__ A, float* __restrict__ Out) {
    const int row  = blockIdx.x;
    const int tid  = threadIdx.x;
    const int lane = tid & 63;
    const int wave = tid >> 6;

    __shared__ unsigned hist[NBINS];
    __shared__ float    cv[CAP];
    __shared__ int      cc[CAP];
    __shared__ float    bbv[BB];
    __shared__ int      bbc[BB];
    __shared__ float    pval[PSLOT][BLOCK];   // transposed: stride-1 reads
    __shared__ int      pcol[PSLOT][BLOCK];
    __shared__ unsigned pcnt[BLOCK];
    __shared__ unsigned ccnt;
    __shared__ int      fb;                   // fallback flag

    #pragma unroll
    for (int i = 0; i < (NBINS - SPEC_BASE) / BLOCK; ++i)
        hist[SPEC_BASE + tid + i * BLOCK] = 0u;
    pcnt[tid] = 0u;
    if (tid == 0) { ccnt = 0u; fb = 0; }
    __syncthreads();

    // ---- touch 1: the ONLY global read of A on the fast path ----
    const f4* __restrict__ Arow = reinterpret_cast<const f4*>(A + (size_t)row * N);
    #pragma unroll
    for (int i = 0; i < 8; ++i) {
        f4 v = Arow[i * BLOCK + tid];
        #pragma unroll
        for (int c = 0; c < 4; ++c) {
            float f = v[c];
            if (f > TSPEC) {
                atomicAdd(&hist[__float_as_uint(f) >> 20], 1u);
                unsigned ix = atomicAdd(&ccnt, 1u);
                if (ix < CAP) { cv[ix] = f; cc[ix] = (i * BLOCK + tid) * 4 + c; }
            }
        }
    }
    __syncthreads();

    f4* __restrict__ Orow4 = reinterpret_cast<f4*>(Out + (size_t)row * N);

    // ---- selection: WAVE 0 ONLY (waves 1-3 go straight to the barrier) ----
    if (wave == 0) {
        int B, G;
        bool ok = find_cutoff<16>(hist, lane, SPEC_BASE, B, G);
        const unsigned Call = ccnt;
        if (!ok || Call > (unsigned)CAP) {
            fb = 1;
        } else {
            const int R = K - G;            // boundary rank within bin B (>=1)
            const int C = (int)Call;
            // compact bin-B entries
            int total = 0;
            #pragma unroll
            for (int s = 0; s < SLOTS; ++s) {
                const int j = lane + s * 64;
                bool flag = false; float fv = 0.0f; int fc = 0;
                if (j < C) {
                    fv = cv[j];
                    if ((int)(__float_as_uint(fv) >> 20) == B) { flag = true; fc = cc[j]; }
                }
                unsigned long long m = __ballot(flag);
                if (flag) {
                    int pos = total + __popcll(m & ((1ull << lane) - 1ull));
                    if (pos < BB) { bbv[pos] = fv; bbc[pos] = fc; }
                }
                total += (int)__popcll(m);
            }
            if (total > BB) {
                fb = 1;                     // adversarial tie overflow
            } else {
                const int T = total;        // expected ~26; >= R
                float mv0 = -1.0f, mv1 = -1.0f; int mc0 = 0x7fffffff, mc1 = 0x7fffffff;
                if (lane      < T) { mv0 = bbv[lane];      mc0 = bbc[lane]; }
                if (lane + 64 < T) { mv1 = bbv[lane + 64]; mc1 = bbc[lane + 64]; }
                int r0 = 0, r1 = 0;
                for (int j = 0; j < T; ++j) {    // LDS broadcast reads
                    const float vj = bbv[j];
                    const int   cj = bbc[j];
                    if (vj > mv0 || (vj == mv0 && cj < mc0)) r0++;
                    if (vj > mv1 || (vj == mv1 && cj < mc1)) r1++;
                }
                float bv = 0.0f; int bc = -1; bool found = false;
                if (lane      < T && r0 == R - 1) { bv = mv0; bc = mc0; found = true; }
                if (lane + 64 < T && r1 == R - 1) { bv = mv1; bc = mc1; found = true; }
                float vR = __int_as_float(0x7f800000);
                int   cR = -1;
                unsigned long long bm = __ballot(found);
                if (bm != 0ull) {
                    int src = (int)__ffsll((long long)bm) - 1;
                    vR = __shfl(bv, src, 64);
                    cR = __shfl(bc, src, 64);
                }
                // scatter the exactly-K selected pairs to their owner threads
                #pragma unroll
                for (int s = 0; s < SLOTS; ++s) {
                    const int j = lane + s * 64;
                    if (j < C) {
                        float fv = cv[j]; int fc = cc[j];
                        if (fv > vR || (fv == vR && fc <= cR)) {
                            int owner = (fc >> 2) & (BLOCK - 1);
                            unsigned p = atomicAdd(&pcnt[owner], 1u);
                            if (p < (unsigned)PSLOT) {
                                pval[p][owner] = fv;
                                pcol[p][owner] = fc;
                            } else {
                                fb = 1;     // >PSLOT per owner (rare)
                            }
                        }
                    }
                }
            }
        }
    }
    __syncthreads();   // LDS-only barrier: no global stores outstanding

    if (!fb) {
        // ---- emit: zero + own patches; ONE nt burst, kernel ends ----
        const unsigned cnt = pcnt[tid];
        const float v0 = pval[0][tid], v1 = pval[1][tid],
                    v2 = pval[2][tid], v3 = pval[3][tid];
        const int   c0 = pcol[0][tid], c1 = pcol[1][tid],
                    c2 = pcol[2][tid], c3 = pcol[3][tid];
        unsigned m8 = 0;
        if (cnt > 0) m8 |= 1u << (c0 >> 10);
        if (cnt > 1) m8 |= 1u << (c1 >> 10);
        if (cnt > 2) m8 |= 1u << (c2 >> 10);
        if (cnt > 3) m8 |= 1u << (c3 >> 10);
        #pragma unroll
        for (int i = 0; i < 8; ++i) {
            f4 w = {0.0f, 0.0f, 0.0f, 0.0f};
            if (m8 & (1u << i)) {
                #define APPLY(CC, VV, KI)                                          \
                    if (cnt > (KI) && ((CC) >> 10) == i) {                         \
                        const int cm = (CC) & 3;                                   \
                        w[0] = (cm == 0) ? (VV) : w[0];                            \
                        w[1] = (cm == 1) ? (VV) : w[1];                            \
                        w[2] = (cm == 2) ? (VV) : w[2];                            \
                        w[3] = (cm == 3) ? (VV) : w[3];                            \
                    }
                APPLY(c0, v0, 0) APPLY(c1, v1, 1) APPLY(c2, v2, 2) APPLY(c3, v3, 3)
                #undef APPLY
            }
            __builtin_nontemporal_store(w, Orow4 + i * BLOCK + tid);
        }
        return;
    }

    // ---- exact fallback (block-uniform; ~never for N(0,1) rows) ----
    #pragma unroll
    for (int i = 0; i < NBINS / BLOCK; ++i) hist[tid + i * BLOCK] = 0u;
    if (tid == 0) ccnt = 0u;
    __syncthreads();
    #pragma unroll
    for (int i = 0; i < 8; ++i) {
        f4 v = Arow[i * BLOCK + tid];
        #pragma unroll
        for (int c = 0; c < 4; ++c) {
            float f = v[c];
            if (f > 0.0f) atomicAdd(&hist[__float_as_uint(f) >> 20], 1u);
        }
    }
    __syncthreads();
    int B, G;
    if (!find_cutoff<32>(hist, lane, 0, B, G)) { B = -1; G = 0; }
    if (B >= 0) {
        #pragma unroll
        for (int i = 0; i < 8; ++i) {
            f4 v = Arow[i * BLOCK + tid];
            #pragma unroll
            for (int c = 0; c < 4; ++c) {
                float f = v[c];
                if (f > 0.0f && (int)(__float_as_uint(f) >> 20) == B) {
                    unsigned ix = atomicAdd(&ccnt, 1u);
                    if (ix < CAP) { cv[ix] = f; cc[ix] = (i * BLOCK + tid) * 4 + c; }
                }
            }
        }
    }
    __syncthreads();

    float vR = 0.0f;                        // B == -1: keep all positives
    int   cR = -1;
    if (B >= 0) {
        const int R = K - G;
        const int C = (int)min(ccnt, (unsigned)CAP);
        float mv[SLOTS]; int mc[SLOTS]; int rk[SLOTS];
        #pragma unroll
        for (int s = 0; s < SLOTS; ++s) {
            const int j = lane + s * 64;
            if (j < C) { mv[s] = cv[j]; mc[s] = cc[j]; }
            else       { mv[s] = -1.0f; mc[s] = 0x7fffffff; }
            rk[s] = 0;
        }
        for (int j = 0; j < C; ++j) {
            const float vj = cv[j];
            const int   cj = cc[j];
            #pragma unroll
            for (int s = 0; s < SLOTS; ++s)
                if (vj > mv[s] || (vj == mv[s] && cj < mc[s])) rk[s]++;
        }
        float bv = 0.0f; int bc = -1; bool found = false;
        #pragma unroll
        for (int s = 0; s < SLOTS; ++s)
            if (lane + s * 64 < C && rk[s] == R - 1) { bv = mv[s]; bc = mc[s]; found = true; }
        vR = __int_as_float(0x7f800000);
        unsigned long long bm = __ballot(found);
        if (bm != 0ull) {
            int src = (int)__ffsll((long long)bm) - 1;
            vR = __shfl(bv, src, 64);
            cR = __shfl(bc, src, 64);
        }
    }

    // dense emit (fallback only): re-read row (cache-hot) and write all
    #pragma unroll
    for (int i = 0; i < 8; ++i) {
        f4 v = Arow[i * BLOCK + tid];
        f4 w;
        #pragma unroll
        for (int c = 0; c < 4; ++c) {
            float f   = v[c];
            int   col = (i * BLOCK + tid) * 4 + c;
            w[c] = ((f > vR) || (f == vR && col <= cR)) ? f : 0.0f;
        }
        __builtin_nontemporal_store(w, Orow4 + i * BLOCK + tid);
    }
}

extern "C" void kernel_launch(void* const* d_in, const int* in_sizes, int n_in,
                              void* d_out, int out_size, void* d_ws, size_t ws_size,
                              hipStream_t stream) {
    const float* A   = (const float*)d_in[0];
    float*       Out = (float*)d_out;
    (void)in_sizes; (void)n_in; (void)d_ws; (void)ws_size; (void)out_size;
    topk_relu_kernel<<<dim3(N), dim3(BLOCK), 0, stream>>>(A, Out);
}

// Round 9
// 91.837 us; speedup vs baseline: 1.8050x; 1.0011x over previous
//
#include <hip/hip_runtime.h>

// Row-wise top-K(32) of relu(A), zero elsewhere. N=8192 fp32 per row.
// One 256-thread block per row.
//  - A read from global EXACTLY ONCE   (R4: 2nd stream kills L3 residency)
//  - ONE final nt store burst, NOTHING after it (R5: post-store vm-drain
//    barrier costs ~12 us)
//  - O(1)-per-thread emit via per-owner patch slots (R6: per-chunk LDS
//    search was ~3000 cyc/wave)
//  - LDS <= ~14.3 KB so occupancy is wave-capped at 8 blocks/CU (R7: 23 KB
//    LDS capped occupancy at 58%; latency-bound, not traffic-bound)
//    -> hist shrunk to 1024 bins; hist UNIONed with patch arrays (hist is
//       dead after wave0's find_cutoff; same-wave LDS ops are in-order).
// Flow: touch1 = hist(values>2.0, (bits>>20)-1024) + collect (val,col)>2.0
// into LDS (~186). Wave 0: cutoff bin B, exact (val desc, col asc) rank-R
// boundary, scatter the exactly-K selected pairs to per-owner patch slots
// (owner=(col>>2)&255, <=4 slots, transposed). One LDS barrier. Emit 8 f4
// nt stores per thread (zero except own patches). Exact block-uniform
// fallback (coarser bits>>21 full-range histogram + dense reload-emit).

constexpr int N     = 8192;
constexpr int K     = 32;
constexpr int HB    = 1024;      // histogram bins (both paths)
constexpr int CAP   = 512;       // candidate list capacity (expected ~186)
constexpr int SLOTS = CAP / 64;
constexpr int BB    = 128;       // compacted cutoff-bin entries
constexpr int BLOCK = 256;
constexpr int PSLOT = 4;         // patch slots per owner thread
constexpr float TSPEC = 2.0f;    // bin(2.0): bits>>20 = 1024

typedef float f4 __attribute__((ext_vector_type(4)));

// Cutoff bin B (bin of the K-th largest) and G = count strictly above B,
// over hist[0..1024). PER=16 bins/lane, staggered reads (2 lanes/bank).
__device__ __forceinline__ bool find_cutoff16(const unsigned* hist, int lane,
                                              int& B, int& G) {
    unsigned s = 0;
    #pragma unroll
    for (int i = 0; i < 16; ++i)
        s += hist[lane * 16 + ((i + lane) & 15)];
    unsigned acc = s;                       // inclusive suffix sum over lanes
    #pragma unroll
    for (int off = 1; off < 64; off <<= 1) {
        unsigned t = __shfl_down(acc, off, 64);
        if (lane + off < 64) acc += t;
    }
    unsigned long long m = __ballot(acc >= (unsigned)K);
    if (m == 0ull) return false;
    int g = 63 - __clzll((long long)m);     // highest group with suffix >= K
    unsigned above = (g < 63) ? (unsigned)__shfl((int)acc, g + 1, 64) : 0u;
    unsigned h  = (lane < 16) ? hist[g * 16 + lane] : 0u;
    unsigned a2 = h;                        // within-group suffix
    #pragma unroll
    for (int off = 1; off < 64; off <<= 1) {
        unsigned t = __shfl_down(a2, off, 64);
        if (lane + off < 64) a2 += t;
    }
    unsigned long long m2 = __ballot(above + a2 >= (unsigned)K);
    int bl = 63 - __clzll((long long)m2);
    B = g * 16 + bl;
    G = (int)(above + (unsigned)__shfl((int)a2, bl, 64)
                    - (unsigned)__shfl((int)h,  bl, 64));
    return true;
}

struct Patches {
    float pval[PSLOT][BLOCK];    // transposed: stride-1 reads at emit
    int   pcol[PSLOT][BLOCK];
};
union USpace {                   // hist dead after find_cutoff -> reuse
    unsigned hist[HB];           // 4 KB
    Patches  p;                  // 8 KB
};

__global__ __launch_bounds__(BLOCK)
void topk_relu_kernel(const float* __restrict__ A, float* __restrict__ Out) {
    const int row  = blockIdx.x;
    const int tid  = threadIdx.x;
    const int lane = tid & 63;
    const int wave = tid >> 6;

    __shared__ USpace   u;
    __shared__ float    cv[CAP];
    __shared__ int      cc[CAP];
    __shared__ float    bbv[BB];
    __shared__ int      bbc[BB];
    __shared__ unsigned pcnt[BLOCK];
    __shared__ unsigned ccnt;
    __shared__ int      fb;

    #pragma unroll
    for (int i = 0; i < HB / BLOCK; ++i) u.hist[tid + i * BLOCK] = 0u;
    pcnt[tid] = 0u;
    if (tid == 0) { ccnt = 0u; fb = 0; }
    __syncthreads();

    // ---- touch 1: the ONLY global read of A on the fast path ----
    const f4* __restrict__ Arow = reinterpret_cast<const f4*>(A + (size_t)row * N);
    #pragma unroll
    for (int i = 0; i < 8; ++i) {
        f4 v = Arow[i * BLOCK + tid];
        #pragma unroll
        for (int c = 0; c < 4; ++c) {
            float f = v[c];
            if (f > TSPEC) {
                atomicAdd(&u.hist[(__float_as_uint(f) >> 20) - 1024], 1u);
                unsigned ix = atomicAdd(&ccnt, 1u);
                if (ix < CAP) { cv[ix] = f; cc[ix] = (i * BLOCK + tid) * 4 + c; }
            }
        }
    }
    __syncthreads();

    f4* __restrict__ Orow4 = reinterpret_cast<f4*>(Out + (size_t)row * N);

    // ---- selection: WAVE 0 ONLY (waves 1-3 fall through to the barrier) ----
    if (wave == 0) {
        int B, G;
        bool ok = find_cutoff16(u.hist, lane, B, G);
        const unsigned Call = ccnt;
        if (!ok || Call > (unsigned)CAP) {
            fb = 1;
        } else {
            const int R = K - G;            // boundary rank within bin B (>=1)
            const int C = (int)Call;
            // compact bin-B entries into bbv/bbc
            int total = 0;
            #pragma unroll
            for (int s = 0; s < SLOTS; ++s) {
                const int j = lane + s * 64;
                bool flag = false; float fv = 0.0f; int fc = 0;
                if (j < C) {
                    fv = cv[j];
                    if ((int)((__float_as_uint(fv) >> 20) - 1024) == B) {
                        flag = true; fc = cc[j];
                    }
                }
                unsigned long long m = __ballot(flag);
                if (flag) {
                    int pos = total + __popcll(m & ((1ull << lane) - 1ull));
                    if (pos < BB) { bbv[pos] = fv; bbc[pos] = fc; }
                }
                total += (int)__popcll(m);
            }
            if (total > BB) {
                fb = 1;                     // adversarial tie overflow
            } else {
                const int T = total;        // expected ~26; >= R
                float mv0 = -1.0f, mv1 = -1.0f; int mc0 = 0x7fffffff, mc1 = 0x7fffffff;
                if (lane      < T) { mv0 = bbv[lane];      mc0 = bbc[lane]; }
                if (lane + 64 < T) { mv1 = bbv[lane + 64]; mc1 = bbc[lane + 64]; }
                int r0 = 0, r1 = 0;
                for (int j = 0; j < T; ++j) {    // LDS broadcast reads
                    const float vj = bbv[j];
                    const int   cj = bbc[j];
                    if (vj > mv0 || (vj == mv0 && cj < mc0)) r0++;
                    if (vj > mv1 || (vj == mv1 && cj < mc1)) r1++;
                }
                float bv = 0.0f; int bc = -1; bool found = false;
                if (lane      < T && r0 == R - 1) { bv = mv0; bc = mc0; found = true; }
                if (lane + 64 < T && r1 == R - 1) { bv = mv1; bc = mc1; found = true; }
                float vR = __int_as_float(0x7f800000);
                int   cR = -1;
                unsigned long long bm = __ballot(found);
                if (bm != 0ull) {
                    int src = (int)__ffsll((long long)bm) - 1;
                    vR = __shfl(bv, src, 64);
                    cR = __shfl(bc, src, 64);
                }
                // scatter the exactly-K selected pairs to their owner threads.
                // Overwrites u.hist (dead): same-wave LDS ops are in-order.
                #pragma unroll
                for (int s = 0; s < SLOTS; ++s) {
                    const int j = lane + s * 64;
                    if (j < C) {
                        float fv = cv[j]; int fc = cc[j];
                        if (fv > vR || (fv == vR && fc <= cR)) {
                            int owner = (fc >> 2) & (BLOCK - 1);
                            unsigned p = atomicAdd(&pcnt[owner], 1u);
                            if (p < (unsigned)PSLOT) {
                                u.p.pval[p][owner] = fv;
                                u.p.pcol[p][owner] = fc;
                            } else {
                                fb = 1;     // >PSLOT per owner (rare)
                            }
                        }
                    }
                }
            }
        }
    }
    __syncthreads();   // LDS-only barrier: no global stores outstanding

    if (!fb) {
        // ---- emit: zero + own patches; ONE nt burst, kernel ends ----
        const unsigned cnt = pcnt[tid];
        const float v0 = u.p.pval[0][tid], v1 = u.p.pval[1][tid],
                    v2 = u.p.pval[2][tid], v3 = u.p.pval[3][tid];
        const int   c0 = u.p.pcol[0][tid], c1 = u.p.pcol[1][tid],
                    c2 = u.p.pcol[2][tid], c3 = u.p.pcol[3][tid];
        unsigned m8 = 0;
        if (cnt > 0) m8 |= 1u << (c0 >> 10);
        if (cnt > 1) m8 |= 1u << (c1 >> 10);
        if (cnt > 2) m8 |= 1u << (c2 >> 10);
        if (cnt > 3) m8 |= 1u << (c3 >> 10);
        #pragma unroll
        for (int i = 0; i < 8; ++i) {
            f4 w = {0.0f, 0.0f, 0.0f, 0.0f};
            if (m8 & (1u << i)) {
                #define APPLY(CC, VV, KI)                                          \
                    if (cnt > (KI) && ((CC) >> 10) == i) {                         \
                        const int cm = (CC) & 3;                                   \
                        w[0] = (cm == 0) ? (VV) : w[0];                            \
                        w[1] = (cm == 1) ? (VV) : w[1];                            \
                        w[2] = (cm == 2) ? (VV) : w[2];                            \
                        w[3] = (cm == 3) ? (VV) : w[3];                            \
                    }
                APPLY(c0, v0, 0) APPLY(c1, v1, 1) APPLY(c2, v2, 2) APPLY(c3, v3, 3)
                #undef APPLY
            }
            __builtin_nontemporal_store(w, Orow4 + i * BLOCK + tid);
        }
        return;
    }

    // ---- exact fallback (block-uniform; ~never for N(0,1) rows) ----
    // coarser full-range binning: bits>>21 in [0, 1024), still monotonic.
    #pragma unroll
    for (int i = 0; i < HB / BLOCK; ++i) u.hist[tid + i * BLOCK] = 0u;
    if (tid == 0) ccnt = 0u;
    __syncthreads();
    #pragma unroll
    for (int i = 0; i < 8; ++i) {
        f4 v = Arow[i * BLOCK + tid];
        #pragma unroll
        for (int c = 0; c < 4; ++c) {
            float f = v[c];
            if (f > 0.0f) atomicAdd(&u.hist[__float_as_uint(f) >> 21], 1u);
        }
    }
    __syncthreads();
    int B, G;
    if (!find_cutoff16(u.hist, lane, B, G)) { B = -1; G = 0; }
    if (B >= 0) {
        #pragma unroll
        for (int i = 0; i < 8; ++i) {
            f4 v = Arow[i * BLOCK + tid];
            #pragma unroll
            for (int c = 0; c < 4; ++c) {
                float f = v[c];
                if (f > 0.0f && (int)(__float_as_uint(f) >> 21) == B) {
                    unsigned ix = atomicAdd(&ccnt, 1u);
                    if (ix < CAP) { cv[ix] = f; cc[ix] = (i * BLOCK + tid) * 4 + c; }
                }
            }
        }
    }
    __syncthreads();

    float vR = 0.0f;                        // B == -1: keep all positives
    int   cR = -1;
    if (B >= 0) {
        const int R = K - G;
        const int C = (int)min(ccnt, (unsigned)CAP);
        float mv[SLOTS]; int mc[SLOTS]; int rk[SLOTS];
        #pragma unroll
        for (int s = 0; s < SLOTS; ++s) {
            const int j = lane + s * 64;
            if (j < C) { mv[s] = cv[j]; mc[s] = cc[j]; }
            else       { mv[s] = -1.0f; mc[s] = 0x7fffffff; }
            rk[s] = 0;
        }
        for (int j = 0; j < C; ++j) {
            const float vj = cv[j];
            const int   cj = cc[j];
            #pragma unroll
            for (int s = 0; s < SLOTS; ++s)
                if (vj > mv[s] || (vj == mv[s] && cj < mc[s])) rk[s]++;
        }
        float bv = 0.0f; int bc = -1; bool found = false;
        #pragma unroll
        for (int s = 0; s < SLOTS; ++s)
            if (lane + s * 64 < C && rk[s] == R - 1) { bv = mv[s]; bc = mc[s]; found = true; }
        vR = __int_as_float(0x7f800000);
        unsigned long long bm = __ballot(found);
        if (bm != 0ull) {
            int src = (int)__ffsll((long long)bm) - 1;
            vR = __shfl(bv, src, 64);
            cR = __shfl(bc, src, 64);
        }
    }

    // dense emit (fallback only): re-read row (cache-hot) and write all
    #pragma unroll
    for (int i = 0; i < 8; ++i) {
        f4 v = Arow[i * BLOCK + tid];
        f4 w;
        #pragma unroll
        for (int c = 0; c < 4; ++c) {
            float f   = v[c];
            int   col = (i * BLOCK + tid) * 4 + c;
            w[c] = ((f > vR) || (f == vR && col <= cR)) ? f : 0.0f;
        }
        __builtin_nontemporal_store(w, Orow4 + i * BLOCK + tid);
    }
}

extern "C" void kernel_launch(void* const* d_in, const int* in_sizes, int n_in,
                              void* d_out, int out_size, void* d_ws, size_t ws_size,
                              hipStream_t stream) {
    const float* A   = (const float*)d_in[0];
    float*       Out = (float*)d_out;
    (void)in_sizes; (void)n_in; (void)d_ws; (void)ws_size; (void)out_size;
    topk_relu_kernel<<<dim3(N), dim3(BLOCK), 0, stream>>>(A, Out);
}